// Round 1
// 563.954 us; speedup vs baseline: 1.1655x; 1.1655x over previous
//
#include <hip/hip_runtime.h>
#include <stdint.h>

// ---------------------------------------------------------------------------
// Block-sparse MoE SwiGLU FFN (stk topology, balanced experts).
//   E=8, TOKENS=16384 (2048/expert), D=2048, HIDDEN=8192 (1024/expert)
//   out[e,t,:] = (silu(x_e w1_e^T) * (x_e w2_e^T)) @ w3_e
// R3: deep-pipelined GEMMs (T2+T3+T4+T5):
//   - 512 threads / 8 waves, 256-scale tiles, BK=32
//   - 4-slot LDS ring, depth-3 prefetch, counted s_waitcnt vmcnt(8),
//     ONE raw s_barrier per K-step (no vmcnt(0) drain in main loop)
//   - XOR swizzle (chunk ^= (row>>1)&3): pre-swizzled global source +
//     swizzled ds_read -> 2-way (free) instead of 8-way bank conflicts
//   - s_setprio(1) around the MFMA cluster
// ---------------------------------------------------------------------------

#define NEXP   8
#define TOKENS 16384
#define D_IN   2048
#define HIDDEN 8192
#define T_E    2048   // tokens per expert
#define H_E    1024   // hidden per expert

typedef __attribute__((ext_vector_type(8))) __bf16 bf16x8;
typedef __attribute__((ext_vector_type(4))) float  f32x4;

__device__ __forceinline__ void async_ld16(const void* g, void* l) {
  __builtin_amdgcn_global_load_lds(
      (const __attribute__((address_space(1))) void*)g,
      (__attribute__((address_space(3))) void*)l, 16, 0, 0);
}

__device__ __forceinline__ unsigned short f2bf(float f) {
  union { float f; uint32_t u; } c; c.f = f;
  uint32_t u = c.u;
  u += 0x7FFFu + ((u >> 16) & 1u);   // round-to-nearest-even
  return (unsigned short)(u >> 16);
}

// 8x8 tile grid -> 2x2 groups (L2 working set ~2-4MB per group)
__device__ __forceinline__ void tile_map(int s, int& mt, int& nt) {
  int g = s >> 2, w = s & 3;
  mt = (g & 3) * 2 + (w & 1);
  nt = (g >> 2) * 2 + (w >> 1);
}

// ---------------- fp32 -> bf16 elementwise convert (4 elems/thread) --------
__global__ __launch_bounds__(256) void cvt_kernel(
    const float* __restrict__ in, unsigned short* __restrict__ out, int n4) {
  int i = blockIdx.x * 256 + threadIdx.x;
  if (i >= n4) return;
  float4 v = ((const float4*)in)[i];
  ushort4 r;
  r.x = f2bf(v.x); r.y = f2bf(v.y); r.z = f2bf(v.z); r.w = f2bf(v.w);
  ((ushort4*)out)[i] = r;
}

// ---------------- w3 [HIDDEN][D] fp32 -> w3t [E][D][H_E] bf16 --------------
__global__ __launch_bounds__(256) void transpose_w3_kernel(
    const float* __restrict__ w3, unsigned short* __restrict__ w3t) {
  __shared__ unsigned short tile[32][33];
  const int d0 = blockIdx.x * 32;
  const int h0 = blockIdx.y * 32;
  const int tx = threadIdx.x;       // 0..31
  const int ty = threadIdx.y;       // 0..7
#pragma unroll
  for (int j = 0; j < 32; j += 8)
    tile[ty + j][tx] = f2bf(w3[(size_t)(h0 + ty + j) * D_IN + d0 + tx]);
  __syncthreads();
  const int e   = h0 >> 10;
  const int hl0 = h0 & 1023;
#pragma unroll
  for (int j = 0; j < 32; j += 8)
    w3t[((size_t)e * D_IN + d0 + ty + j) * H_E + hl0 + tx] = tile[tx][ty + j];
}

// ---------------- GEMM1 fused: g = silu(x w1^T) * (x w2^T) -----------------
// Block tile 256(M) x 128(N_h), dual-B. 8 waves in 2Mx4N; per wave
// 128x32 output for BOTH matrices. LDS: A 4x16KB, B1 4x8KB, B2 4x8KB = 128KB.
__global__ __launch_bounds__(512, 2) void gemm1_kernel(
    const unsigned short* __restrict__ xb,   // [E*T_E][D_IN] bf16
    const unsigned short* __restrict__ w1b,  // [HIDDEN][D_IN]
    const unsigned short* __restrict__ w2b,
    unsigned short* __restrict__ g)          // [E*T_E][H_E] bf16
{
  extern __shared__ char lds[];
  char* const AsB  = lds;            // 4 slots x 16384 : A [256][32] bf16
  char* const B1sB = lds + 65536;    // 4 slots x 8192  : B1 [128][32]
  char* const B2sB = lds + 98304;    // 4 slots x 8192  : B2 [128][32]

  const int bid = blockIdx.x;
  const int e   = bid & 7;           // expert -> XCD affinity
  int mt, nt; tile_map(bid >> 3, mt, nt);
  const int m0 = mt * 256;
  const int n0 = nt * 128;

  const unsigned short* A  = xb  + (size_t)e * T_E * D_IN + (size_t)m0 * D_IN;
  const unsigned short* B1 = w1b + (size_t)e * H_E * D_IN + (size_t)n0 * D_IN;
  const unsigned short* B2 = w2b + (size_t)e * H_E * D_IN + (size_t)n0 * D_IN;

  const int tid  = threadIdx.x;
  const int wave = tid >> 6;
  const int lane = tid & 63;
  const int wm   = wave >> 2;        // 0..1 -> 128 rows
  const int wn   = wave & 3;         // 0..3 -> 32 h-cols
  const int lm   = lane & 15;
  const int qs   = lane >> 4;        // k-chunk 0..3 (8 bf16 each)

  // staging: thread -> (row = tid>>2, chunk = tid&3); source chunk
  // pre-swizzled so linear global_load_lds dest + swizzled ds_read match.
  const int srow   = tid >> 2;            // 0..127
  const int schunk = tid & 3;
  const int sc     = (schunk ^ ((srow >> 1) & 3)) * 8;  // bf16 offset
  const unsigned short* aS0 = A  + (size_t)srow * D_IN + sc;
  const unsigned short* aS1 = A  + (size_t)(128 + srow) * D_IN + sc;
  const unsigned short* b1S = B1 + (size_t)srow * D_IN + sc;
  const unsigned short* b2S = B2 + (size_t)srow * D_IN + sc;
  char* const ldsA0 = AsB  + tid * 16;
  char* const ldsA1 = AsB  + 8192 + tid * 16;
  char* const ldsB1 = B1sB + tid * 16;
  char* const ldsB2 = B2sB + tid * 16;

  // swizzled LDS read offsets (byte): row*64 + (qs ^ ((row>>1)&3))*16
  int offA[8], offB[2];
#pragma unroll
  for (int mi = 0; mi < 8; ++mi) {
    int r = wm * 128 + mi * 16 + lm;
    offA[mi] = r * 64 + ((qs ^ ((r >> 1) & 3)) * 16);
  }
#pragma unroll
  for (int ni = 0; ni < 2; ++ni) {
    int r = wn * 32 + ni * 16 + lm;
    offB[ni] = r * 64 + ((qs ^ ((r >> 1) & 3)) * 16);
  }

  f32x4 acc1[8][2], acc2[8][2];
#pragma unroll
  for (int mi = 0; mi < 8; ++mi)
#pragma unroll
    for (int ni = 0; ni < 2; ++ni) {
      acc1[mi][ni] = (f32x4){0.f, 0.f, 0.f, 0.f};
      acc2[mi][ni] = (f32x4){0.f, 0.f, 0.f, 0.f};
    }

#define G1_STAGE(t)                                          \
  { const int sl_ = (t) & 3;                                 \
    async_ld16(aS0 + (t) * 32, ldsA0 + sl_ * 16384);         \
    async_ld16(aS1 + (t) * 32, ldsA1 + sl_ * 16384);         \
    async_ld16(b1S + (t) * 32, ldsB1 + sl_ * 8192);          \
    async_ld16(b2S + (t) * 32, ldsB2 + sl_ * 8192); }

  G1_STAGE(0); G1_STAGE(1); G1_STAGE(2);   // 12 loads in flight

  const int NT = D_IN / 32;   // 64 K-steps
  for (int t = 0; t < NT; ++t) {
    // counted wait: tile t's 4 loads (oldest) landed; t+1/t+2 stay in flight
    if (t < NT - 2)       asm volatile("s_waitcnt vmcnt(8)" ::: "memory");
    else if (t == NT - 2) asm volatile("s_waitcnt vmcnt(4)" ::: "memory");
    else                  asm volatile("s_waitcnt vmcnt(0)" ::: "memory");
    __builtin_amdgcn_s_barrier();     // raw barrier: no implicit drains
    __builtin_amdgcn_sched_barrier(0);
    if (t + 3 < NT) { G1_STAGE(t + 3); }  // overwrites slot[(t-1)&3]: reads
                                          // of t-1 drained before barrier

    const char* At  = AsB  + (t & 3) * 16384;
    const char* B1t = B1sB + (t & 3) * 8192;
    const char* B2t = B2sB + (t & 3) * 8192;
    bf16x8 af[8], b1f[2], b2f[2];
#pragma unroll
    for (int ni = 0; ni < 2; ++ni) {
      b1f[ni] = *(const bf16x8*)(B1t + offB[ni]);
      b2f[ni] = *(const bf16x8*)(B2t + offB[ni]);
    }
#pragma unroll
    for (int mi = 0; mi < 8; ++mi)
      af[mi] = *(const bf16x8*)(At + offA[mi]);

    __builtin_amdgcn_s_setprio(1);
#pragma unroll
    for (int mi = 0; mi < 8; ++mi)
#pragma unroll
      for (int ni = 0; ni < 2; ++ni) {
        acc1[mi][ni] = __builtin_amdgcn_mfma_f32_16x16x32_bf16(
            af[mi], b1f[ni], acc1[mi][ni], 0, 0, 0);
        acc2[mi][ni] = __builtin_amdgcn_mfma_f32_16x16x32_bf16(
            af[mi], b2f[ni], acc2[mi][ni], 0, 0, 0);
      }
    __builtin_amdgcn_s_setprio(0);
    // drain this wave's ds_reads before next barrier (slot reuse safety)
    asm volatile("s_waitcnt lgkmcnt(0)" ::: "memory");
    __builtin_amdgcn_sched_barrier(0);
  }
#undef G1_STAGE

  // epilogue: g = silu(h1) * h2, bf16 store
  unsigned short* grow = g + (size_t)e * T_E * H_E;
  const int q4 = qs * 4;
#pragma unroll
  for (int mi = 0; mi < 8; ++mi) {
    const int row = m0 + wm * 128 + mi * 16 + q4;
#pragma unroll
    for (int ni = 0; ni < 2; ++ni) {
      const int col = n0 + wn * 32 + ni * 16 + lm;
#pragma unroll
      for (int r = 0; r < 4; ++r) {
        float v1 = acc1[mi][ni][r];
        float v2 = acc2[mi][ni][r];
        float gv = (v1 / (1.0f + __expf(-v1))) * v2;
        grow[(size_t)(row + r) * H_E + col] = f2bf(gv);
      }
    }
  }
}

// ---------------- GEMM2: out = g @ w3t^T (per expert), fp32 out ------------
// Block tile 256x256, BK=32; 8 waves in 2Mx4N, 128x64 per wave.
// LDS: A 4x16KB + B 4x16KB = 128KB.
__global__ __launch_bounds__(512, 2) void gemm2_kernel(
    const unsigned short* __restrict__ g,    // [E*T_E][H_E] bf16
    const unsigned short* __restrict__ w3t,  // [E][D_IN][H_E] bf16
    float* __restrict__ out)                 // [TOKENS][D_IN] fp32
{
  extern __shared__ char lds[];
  char* const AsB = lds;           // 4 slots x 16384 : A [256][32]
  char* const BsB = lds + 65536;   // 4 slots x 16384 : B [256][32]

  const int bid = blockIdx.x;
  const int e   = bid & 7;
  int mt, nt; tile_map(bid >> 3, mt, nt);
  const int m0 = mt * 256;   // tokens
  const int n0 = nt * 256;   // D

  const unsigned short* A = g   + (size_t)e * T_E * H_E  + (size_t)m0 * H_E;
  const unsigned short* B = w3t + (size_t)e * D_IN * H_E + (size_t)n0 * H_E;

  const int tid  = threadIdx.x;
  const int wave = tid >> 6;
  const int lane = tid & 63;
  const int wm   = wave >> 2;
  const int wn   = wave & 3;
  const int lm   = lane & 15;
  const int qs   = lane >> 4;

  const int srow   = tid >> 2;
  const int schunk = tid & 3;
  const int sc     = (schunk ^ ((srow >> 1) & 3)) * 8;
  const unsigned short* aS0 = A + (size_t)srow * H_E + sc;
  const unsigned short* aS1 = A + (size_t)(128 + srow) * H_E + sc;
  const unsigned short* bS0 = B + (size_t)srow * H_E + sc;
  const unsigned short* bS1 = B + (size_t)(128 + srow) * H_E + sc;
  char* const ldsA0 = AsB + tid * 16;
  char* const ldsA1 = AsB + 8192 + tid * 16;
  char* const ldsB0 = BsB + tid * 16;
  char* const ldsB1 = BsB + 8192 + tid * 16;

  int offA[8], offB[4];
#pragma unroll
  for (int mi = 0; mi < 8; ++mi) {
    int r = wm * 128 + mi * 16 + lm;
    offA[mi] = r * 64 + ((qs ^ ((r >> 1) & 3)) * 16);
  }
#pragma unroll
  for (int ni = 0; ni < 4; ++ni) {
    int r = wn * 64 + ni * 16 + lm;
    offB[ni] = r * 64 + ((qs ^ ((r >> 1) & 3)) * 16);
  }

  f32x4 acc[8][4];
#pragma unroll
  for (int mi = 0; mi < 8; ++mi)
#pragma unroll
    for (int ni = 0; ni < 4; ++ni) acc[mi][ni] = (f32x4){0.f, 0.f, 0.f, 0.f};

#define G2_STAGE(t)                                          \
  { const int sl_ = (t) & 3;                                 \
    async_ld16(aS0 + (t) * 32, ldsA0 + sl_ * 16384);         \
    async_ld16(aS1 + (t) * 32, ldsA1 + sl_ * 16384);         \
    async_ld16(bS0 + (t) * 32, ldsB0 + sl_ * 16384);         \
    async_ld16(bS1 + (t) * 32, ldsB1 + sl_ * 16384); }

  G2_STAGE(0); G2_STAGE(1); G2_STAGE(2);

  const int NT = H_E / 32;   // 32 K-steps
  for (int t = 0; t < NT; ++t) {
    if (t < NT - 2)       asm volatile("s_waitcnt vmcnt(8)" ::: "memory");
    else if (t == NT - 2) asm volatile("s_waitcnt vmcnt(4)" ::: "memory");
    else                  asm volatile("s_waitcnt vmcnt(0)" ::: "memory");
    __builtin_amdgcn_s_barrier();
    __builtin_amdgcn_sched_barrier(0);
    if (t + 3 < NT) { G2_STAGE(t + 3); }

    const char* At = AsB + (t & 3) * 16384;
    const char* Bt = BsB + (t & 3) * 16384;
    bf16x8 af[8], bfr[4];
#pragma unroll
    for (int ni = 0; ni < 4; ++ni)
      bfr[ni] = *(const bf16x8*)(Bt + offB[ni]);
#pragma unroll
    for (int mi = 0; mi < 8; ++mi)
      af[mi] = *(const bf16x8*)(At + offA[mi]);

    __builtin_amdgcn_s_setprio(1);
#pragma unroll
    for (int mi = 0; mi < 8; ++mi)
#pragma unroll
      for (int ni = 0; ni < 4; ++ni)
        acc[mi][ni] = __builtin_amdgcn_mfma_f32_16x16x32_bf16(
            af[mi], bfr[ni], acc[mi][ni], 0, 0, 0);
    __builtin_amdgcn_s_setprio(0);
    asm volatile("s_waitcnt lgkmcnt(0)" ::: "memory");
    __builtin_amdgcn_sched_barrier(0);
  }
#undef G2_STAGE

  float* orow = out + (size_t)e * T_E * D_IN;
  const int q4 = qs * 4;
#pragma unroll
  for (int mi = 0; mi < 8; ++mi) {
    const int row = m0 + wm * 128 + mi * 16 + q4;
#pragma unroll
    for (int ni = 0; ni < 4; ++ni) {
      const int col = n0 + wn * 64 + ni * 16 + lm;
#pragma unroll
      for (int r = 0; r < 4; ++r)
        orow[(size_t)(row + r) * D_IN + col] = acc[mi][ni][r];
    }
  }
}

// ---------------------------------------------------------------------------
extern "C" void kernel_launch(void* const* d_in, const int* in_sizes, int n_in,
                              void* d_out, int out_size, void* d_ws, size_t ws_size,
                              hipStream_t stream) {
  const float* x  = (const float*)d_in[0];   // [16384][2048]
  const float* w1 = (const float*)d_in[1];   // [8192][2048]
  const float* w2 = (const float*)d_in[2];
  const float* w3 = (const float*)d_in[3];
  float* out = (float*)d_out;

  // one-time: allow 128KB dynamic LDS for the gemm kernels
  static bool attr_done = false;
  if (!attr_done) {
    hipFuncSetAttribute(reinterpret_cast<const void*>(gemm1_kernel),
                        hipFuncAttributeMaxDynamicSharedMemorySize, 131072);
    hipFuncSetAttribute(reinterpret_cast<const void*>(gemm2_kernel),
                        hipFuncAttributeMaxDynamicSharedMemorySize, 131072);
    attr_done = true;
  }

  // workspace layout (bytes)
  char* ws = (char*)d_ws;
  unsigned short* xb  = (unsigned short*)(ws);                       // 64 MB
  unsigned short* w1b = (unsigned short*)(ws + 67108864);            // 32 MB
  unsigned short* w2b = (unsigned short*)(ws + 100663296);           // 32 MB
  unsigned short* w3t = (unsigned short*)(ws + 134217728);           // 32 MB
  unsigned short* gbuf= (unsigned short*)(ws + 167772160);           // 32 MB

  // 1) convert x, w1, w2 to bf16
  cvt_kernel<<<(TOKENS * D_IN / 4 + 255) / 256, 256, 0, stream>>>(x, xb, TOKENS * D_IN / 4);
  cvt_kernel<<<(HIDDEN * D_IN / 4 + 255) / 256, 256, 0, stream>>>(w1, w1b, HIDDEN * D_IN / 4);
  cvt_kernel<<<(HIDDEN * D_IN / 4 + 255) / 256, 256, 0, stream>>>(w2, w2b, HIDDEN * D_IN / 4);

  // 2) transpose+convert w3 -> [E][D][H_E]
  transpose_w3_kernel<<<dim3(D_IN / 32, HIDDEN / 32), dim3(32, 8), 0, stream>>>(w3, w3t);

  // 3) fused sdd GEMMs + SiLU gate -> g (bf16)
  gemm1_kernel<<<NEXP * 64, 512, 131072, stream>>>(xb, w1b, w2b, gbuf);

  // 4) dsd GEMM -> out (fp32)
  gemm2_kernel<<<NEXP * 64, 512, 131072, stream>>>(gbuf, w3t, out);
}

// Round 2
// 557.327 us; speedup vs baseline: 1.1794x; 1.0119x over previous
//
#include <hip/hip_runtime.h>
#include <stdint.h>

// ---------------------------------------------------------------------------
// Block-sparse MoE SwiGLU FFN (stk topology, balanced experts).
//   E=8, TOKENS=16384 (2048/expert), D=2048, HIDDEN=8192 (1024/expert)
//   out[e,t,:] = (silu(x_e w1_e^T) * (x_e w2_e^T)) @ w3_e
// R4: R3 ring (4-slot, counted vmcnt(8), XOR swizzle, setprio) + 2-phase
// K-step split: each phase = {stage 2 rounds || ds_read half the frags ||
// 16 MFMA}, pinned with sched_barrier(0) so the compiler cannot re-bundle
// the reads. Gives each wave self-overlap of its own reads with its own
// MFMAs (LDS pipe ~1150 cyc/K-step/CU is co-critical with matrix ~1240).
// Also: 3 cvt launches merged into 1.
// ---------------------------------------------------------------------------

#define NEXP   8
#define TOKENS 16384
#define D_IN   2048
#define HIDDEN 8192
#define T_E    2048   // tokens per expert
#define H_E    1024   // hidden per expert

typedef __attribute__((ext_vector_type(8))) __bf16 bf16x8;
typedef __attribute__((ext_vector_type(4))) float  f32x4;

__device__ __forceinline__ void async_ld16(const void* g, void* l) {
  __builtin_amdgcn_global_load_lds(
      (const __attribute__((address_space(1))) void*)g,
      (__attribute__((address_space(3))) void*)l, 16, 0, 0);
}

__device__ __forceinline__ unsigned short f2bf(float f) {
  union { float f; uint32_t u; } c; c.f = f;
  uint32_t u = c.u;
  u += 0x7FFFu + ((u >> 16) & 1u);   // round-to-nearest-even
  return (unsigned short)(u >> 16);
}

// 8x8 tile grid -> 2x2 groups (L2 working set ~2-4MB per group)
__device__ __forceinline__ void tile_map(int s, int& mt, int& nt) {
  int g = s >> 2, w = s & 3;
  mt = (g & 3) * 2 + (w & 1);
  nt = (g >> 2) * 2 + (w >> 1);
}

// ---------------- fp32 -> bf16 convert: x, w1, w2 in one launch ------------
#define X4 (TOKENS * D_IN / 4)     // 8388608
#define W4 (HIDDEN * D_IN / 4)     // 4194304
__global__ __launch_bounds__(256) void cvt3_kernel(
    const float* __restrict__ x,  const float* __restrict__ w1,
    const float* __restrict__ w2,
    unsigned short* __restrict__ xb, unsigned short* __restrict__ w1b,
    unsigned short* __restrict__ w2b) {
  int i = blockIdx.x * 256 + threadIdx.x;
  const float* in; unsigned short* out; int j;
  if (i < X4)            { in = x;  out = xb;  j = i; }
  else if (i < X4 + W4)  { in = w1; out = w1b; j = i - X4; }
  else                   { in = w2; out = w2b; j = i - X4 - W4; }
  float4 v = ((const float4*)in)[j];
  ushort4 r;
  r.x = f2bf(v.x); r.y = f2bf(v.y); r.z = f2bf(v.z); r.w = f2bf(v.w);
  ((ushort4*)out)[j] = r;
}

// ---------------- w3 [HIDDEN][D] fp32 -> w3t [E][D][H_E] bf16 --------------
__global__ __launch_bounds__(256) void transpose_w3_kernel(
    const float* __restrict__ w3, unsigned short* __restrict__ w3t) {
  __shared__ unsigned short tile[32][33];
  const int d0 = blockIdx.x * 32;
  const int h0 = blockIdx.y * 32;
  const int tx = threadIdx.x;       // 0..31
  const int ty = threadIdx.y;       // 0..7
#pragma unroll
  for (int j = 0; j < 32; j += 8)
    tile[ty + j][tx] = f2bf(w3[(size_t)(h0 + ty + j) * D_IN + d0 + tx]);
  __syncthreads();
  const int e   = h0 >> 10;
  const int hl0 = h0 & 1023;
#pragma unroll
  for (int j = 0; j < 32; j += 8)
    w3t[((size_t)e * D_IN + d0 + ty + j) * H_E + hl0 + tx] = tile[tx][ty + j];
}

// ---------------- GEMM1 fused: g = silu(x w1^T) * (x w2^T) -----------------
// Block tile 256(M) x 128(N_h), dual-B. 8 waves in 2Mx4N; per wave
// 128x32 output for BOTH matrices. LDS: A 4x16KB, B1 4x8KB, B2 4x8KB = 128KB.
__global__ __launch_bounds__(512, 2) void gemm1_kernel(
    const unsigned short* __restrict__ xb,   // [E*T_E][D_IN] bf16
    const unsigned short* __restrict__ w1b,  // [HIDDEN][D_IN]
    const unsigned short* __restrict__ w2b,
    unsigned short* __restrict__ g)          // [E*T_E][H_E] bf16
{
  extern __shared__ char lds[];
  char* const AsB  = lds;            // 4 slots x 16384 : A [256][32] bf16
  char* const B1sB = lds + 65536;    // 4 slots x 8192  : B1 [128][32]
  char* const B2sB = lds + 98304;    // 4 slots x 8192  : B2 [128][32]

  const int bid = blockIdx.x;
  const int e   = bid & 7;           // expert -> XCD affinity
  int mt, nt; tile_map(bid >> 3, mt, nt);
  const int m0 = mt * 256;
  const int n0 = nt * 128;

  const unsigned short* A  = xb  + (size_t)e * T_E * D_IN + (size_t)m0 * D_IN;
  const unsigned short* B1 = w1b + (size_t)e * H_E * D_IN + (size_t)n0 * D_IN;
  const unsigned short* B2 = w2b + (size_t)e * H_E * D_IN + (size_t)n0 * D_IN;

  const int tid  = threadIdx.x;
  const int wave = tid >> 6;
  const int lane = tid & 63;
  const int wm   = wave >> 2;        // 0..1 -> 128 rows
  const int wn   = wave & 3;         // 0..3 -> 32 h-cols
  const int lm   = lane & 15;
  const int qs   = lane >> 4;        // k-chunk 0..3 (8 bf16 each)

  // staging: thread -> (row = tid>>2, chunk = tid&3); source chunk
  // pre-swizzled so linear global_load_lds dest + swizzled ds_read match.
  const int srow   = tid >> 2;            // 0..127
  const int schunk = tid & 3;
  const int sc     = (schunk ^ ((srow >> 1) & 3)) * 8;  // bf16 offset
  const unsigned short* aS0 = A  + (size_t)srow * D_IN + sc;
  const unsigned short* aS1 = A  + (size_t)(128 + srow) * D_IN + sc;
  const unsigned short* b1S = B1 + (size_t)srow * D_IN + sc;
  const unsigned short* b2S = B2 + (size_t)srow * D_IN + sc;
  char* const ldsA0 = AsB  + tid * 16;
  char* const ldsA1 = AsB  + 8192 + tid * 16;
  char* const ldsB1 = B1sB + tid * 16;
  char* const ldsB2 = B2sB + tid * 16;

  // swizzled LDS read offsets (byte): row*64 + (qs ^ ((row>>1)&3))*16
  int offA[8], offB[2];
#pragma unroll
  for (int mi = 0; mi < 8; ++mi) {
    int r = wm * 128 + mi * 16 + lm;
    offA[mi] = r * 64 + ((qs ^ ((r >> 1) & 3)) * 16);
  }
#pragma unroll
  for (int ni = 0; ni < 2; ++ni) {
    int r = wn * 32 + ni * 16 + lm;
    offB[ni] = r * 64 + ((qs ^ ((r >> 1) & 3)) * 16);
  }

  f32x4 acc1[8][2], acc2[8][2];
#pragma unroll
  for (int mi = 0; mi < 8; ++mi)
#pragma unroll
    for (int ni = 0; ni < 2; ++ni) {
      acc1[mi][ni] = (f32x4){0.f, 0.f, 0.f, 0.f};
      acc2[mi][ni] = (f32x4){0.f, 0.f, 0.f, 0.f};
    }

#define G1_STAGE(t)                                          \
  { const int sl_ = (t) & 3;                                 \
    async_ld16(aS0 + (t) * 32, ldsA0 + sl_ * 16384);         \
    async_ld16(aS1 + (t) * 32, ldsA1 + sl_ * 16384);         \
    async_ld16(b1S + (t) * 32, ldsB1 + sl_ * 8192);          \
    async_ld16(b2S + (t) * 32, ldsB2 + sl_ * 8192); }

  G1_STAGE(0); G1_STAGE(1); G1_STAGE(2);   // 12 loads in flight

  const int NT = D_IN / 32;   // 64 K-steps
  for (int t = 0; t < NT; ++t) {
    // counted wait: tile t's 4 loads (oldest) landed; t+1/t+2 stay in flight
    if (t < NT - 2)       asm volatile("s_waitcnt vmcnt(8)" ::: "memory");
    else if (t == NT - 2) asm volatile("s_waitcnt vmcnt(4)" ::: "memory");
    else                  asm volatile("s_waitcnt vmcnt(0)" ::: "memory");
    __builtin_amdgcn_s_barrier();     // raw barrier: no implicit drains
    __builtin_amdgcn_sched_barrier(0);

    const char* At  = AsB  + (t & 3) * 16384;
    const char* B1t = B1sB + (t & 3) * 8192;
    const char* B2t = B2sB + (t & 3) * 8192;

    // ---------- phase A: stage 2 rounds of t+3, B frags + A(0..3) ---------
    if (t + 3 < NT) {
      const int sl_ = (t + 3) & 3;
      async_ld16(aS0 + (t + 3) * 32, ldsA0 + sl_ * 16384);
      async_ld16(b1S + (t + 3) * 32, ldsB1 + sl_ * 8192);
    }
    bf16x8 b1f[2], b2f[2], afA[4];
#pragma unroll
    for (int ni = 0; ni < 2; ++ni) {
      b1f[ni] = *(const bf16x8*)(B1t + offB[ni]);
      b2f[ni] = *(const bf16x8*)(B2t + offB[ni]);
    }
#pragma unroll
    for (int mi = 0; mi < 4; ++mi)
      afA[mi] = *(const bf16x8*)(At + offA[mi]);

    __builtin_amdgcn_s_setprio(1);
#pragma unroll
    for (int mi = 0; mi < 4; ++mi)
#pragma unroll
      for (int ni = 0; ni < 2; ++ni) {
        acc1[mi][ni] = __builtin_amdgcn_mfma_f32_16x16x32_bf16(
            afA[mi], b1f[ni], acc1[mi][ni], 0, 0, 0);
        acc2[mi][ni] = __builtin_amdgcn_mfma_f32_16x16x32_bf16(
            afA[mi], b2f[ni], acc2[mi][ni], 0, 0, 0);
      }
    __builtin_amdgcn_s_setprio(0);
    __builtin_amdgcn_sched_barrier(0);   // pin: phase-B reads stay here

    // ---------- phase B: stage 2 rounds of t+3, A(4..7), MFMA mi 4..7 -----
    if (t + 3 < NT) {
      const int sl_ = (t + 3) & 3;
      async_ld16(aS1 + (t + 3) * 32, ldsA1 + sl_ * 16384);
      async_ld16(b2S + (t + 3) * 32, ldsB2 + sl_ * 8192);
    }
    bf16x8 afB[4];
#pragma unroll
    for (int mi = 0; mi < 4; ++mi)
      afB[mi] = *(const bf16x8*)(At + offA[mi + 4]);

    __builtin_amdgcn_s_setprio(1);
#pragma unroll
    for (int mi = 0; mi < 4; ++mi)
#pragma unroll
      for (int ni = 0; ni < 2; ++ni) {
        acc1[mi + 4][ni] = __builtin_amdgcn_mfma_f32_16x16x32_bf16(
            afB[mi], b1f[ni], acc1[mi + 4][ni], 0, 0, 0);
        acc2[mi + 4][ni] = __builtin_amdgcn_mfma_f32_16x16x32_bf16(
            afB[mi], b2f[ni], acc2[mi + 4][ni], 0, 0, 0);
      }
    __builtin_amdgcn_s_setprio(0);
    // drain this wave's ds_reads before next barrier (slot reuse safety)
    asm volatile("s_waitcnt lgkmcnt(0)" ::: "memory");
    __builtin_amdgcn_sched_barrier(0);
  }
#undef G1_STAGE

  // epilogue: g = silu(h1) * h2, bf16 store
  unsigned short* grow = g + (size_t)e * T_E * H_E;
  const int q4 = qs * 4;
#pragma unroll
  for (int mi = 0; mi < 8; ++mi) {
    const int row = m0 + wm * 128 + mi * 16 + q4;
#pragma unroll
    for (int ni = 0; ni < 2; ++ni) {
      const int col = n0 + wn * 32 + ni * 16 + lm;
#pragma unroll
      for (int r = 0; r < 4; ++r) {
        float v1 = acc1[mi][ni][r];
        float v2 = acc2[mi][ni][r];
        float gv = (v1 / (1.0f + __expf(-v1))) * v2;
        grow[(size_t)(row + r) * H_E + col] = f2bf(gv);
      }
    }
  }
}

// ---------------- GEMM2: out = g @ w3t^T (per expert), fp32 out ------------
// Block tile 256x256, BK=32; 8 waves in 2Mx4N, 128x64 per wave.
// LDS: A 4x16KB + B 4x16KB = 128KB.
__global__ __launch_bounds__(512, 2) void gemm2_kernel(
    const unsigned short* __restrict__ g,    // [E*T_E][H_E] bf16
    const unsigned short* __restrict__ w3t,  // [E][D_IN][H_E] bf16
    float* __restrict__ out)                 // [TOKENS][D_IN] fp32
{
  extern __shared__ char lds[];
  char* const AsB = lds;           // 4 slots x 16384 : A [256][32]
  char* const BsB = lds + 65536;   // 4 slots x 16384 : B [256][32]

  const int bid = blockIdx.x;
  const int e   = bid & 7;
  int mt, nt; tile_map(bid >> 3, mt, nt);
  const int m0 = mt * 256;   // tokens
  const int n0 = nt * 256;   // D

  const unsigned short* A = g   + (size_t)e * T_E * H_E  + (size_t)m0 * H_E;
  const unsigned short* B = w3t + (size_t)e * D_IN * H_E + (size_t)n0 * H_E;

  const int tid  = threadIdx.x;
  const int wave = tid >> 6;
  const int lane = tid & 63;
  const int wm   = wave >> 2;
  const int wn   = wave & 3;
  const int lm   = lane & 15;
  const int qs   = lane >> 4;

  const int srow   = tid >> 2;
  const int schunk = tid & 3;
  const int sc     = (schunk ^ ((srow >> 1) & 3)) * 8;
  const unsigned short* aS0 = A + (size_t)srow * H_E + sc;
  const unsigned short* aS1 = A + (size_t)(128 + srow) * H_E + sc;
  const unsigned short* bS0 = B + (size_t)srow * H_E + sc;
  const unsigned short* bS1 = B + (size_t)(128 + srow) * H_E + sc;
  char* const ldsA0 = AsB + tid * 16;
  char* const ldsA1 = AsB + 8192 + tid * 16;
  char* const ldsB0 = BsB + tid * 16;
  char* const ldsB1 = BsB + 8192 + tid * 16;

  int offA[8], offB[4];
#pragma unroll
  for (int mi = 0; mi < 8; ++mi) {
    int r = wm * 128 + mi * 16 + lm;
    offA[mi] = r * 64 + ((qs ^ ((r >> 1) & 3)) * 16);
  }
#pragma unroll
  for (int ni = 0; ni < 4; ++ni) {
    int r = wn * 64 + ni * 16 + lm;
    offB[ni] = r * 64 + ((qs ^ ((r >> 1) & 3)) * 16);
  }

  f32x4 acc[8][4];
#pragma unroll
  for (int mi = 0; mi < 8; ++mi)
#pragma unroll
    for (int ni = 0; ni < 4; ++ni) acc[mi][ni] = (f32x4){0.f, 0.f, 0.f, 0.f};

#define G2_STAGE(t)                                          \
  { const int sl_ = (t) & 3;                                 \
    async_ld16(aS0 + (t) * 32, ldsA0 + sl_ * 16384);         \
    async_ld16(aS1 + (t) * 32, ldsA1 + sl_ * 16384);         \
    async_ld16(bS0 + (t) * 32, ldsB0 + sl_ * 16384);         \
    async_ld16(bS1 + (t) * 32, ldsB1 + sl_ * 16384); }

  G2_STAGE(0); G2_STAGE(1); G2_STAGE(2);

  const int NT = H_E / 32;   // 32 K-steps
  for (int t = 0; t < NT; ++t) {
    if (t < NT - 2)       asm volatile("s_waitcnt vmcnt(8)" ::: "memory");
    else if (t == NT - 2) asm volatile("s_waitcnt vmcnt(4)" ::: "memory");
    else                  asm volatile("s_waitcnt vmcnt(0)" ::: "memory");
    __builtin_amdgcn_s_barrier();
    __builtin_amdgcn_sched_barrier(0);

    const char* At = AsB + (t & 3) * 16384;
    const char* Bt = BsB + (t & 3) * 16384;

    // ---------- phase A ----------
    if (t + 3 < NT) {
      const int sl_ = (t + 3) & 3;
      async_ld16(aS0 + (t + 3) * 32, ldsA0 + sl_ * 16384);
      async_ld16(bS0 + (t + 3) * 32, ldsB0 + sl_ * 16384);
    }
    bf16x8 bfr[4], afA[4];
#pragma unroll
    for (int ni = 0; ni < 4; ++ni)
      bfr[ni] = *(const bf16x8*)(Bt + offB[ni]);
#pragma unroll
    for (int mi = 0; mi < 4; ++mi)
      afA[mi] = *(const bf16x8*)(At + offA[mi]);

    __builtin_amdgcn_s_setprio(1);
#pragma unroll
    for (int mi = 0; mi < 4; ++mi)
#pragma unroll
      for (int ni = 0; ni < 4; ++ni)
        acc[mi][ni] = __builtin_amdgcn_mfma_f32_16x16x32_bf16(
            afA[mi], bfr[ni], acc[mi][ni], 0, 0, 0);
    __builtin_amdgcn_s_setprio(0);
    __builtin_amdgcn_sched_barrier(0);   // pin: phase-B reads stay here

    // ---------- phase B ----------
    if (t + 3 < NT) {
      const int sl_ = (t + 3) & 3;
      async_ld16(aS1 + (t + 3) * 32, ldsA1 + sl_ * 16384);
      async_ld16(bS1 + (t + 3) * 32, ldsB1 + sl_ * 16384);
    }
    bf16x8 afB[4];
#pragma unroll
    for (int mi = 0; mi < 4; ++mi)
      afB[mi] = *(const bf16x8*)(At + offA[mi + 4]);

    __builtin_amdgcn_s_setprio(1);
#pragma unroll
    for (int mi = 0; mi < 4; ++mi)
#pragma unroll
      for (int ni = 0; ni < 4; ++ni)
        acc[mi + 4][ni] = __builtin_amdgcn_mfma_f32_16x16x32_bf16(
            afB[mi], bfr[ni], acc[mi + 4][ni], 0, 0, 0);
    __builtin_amdgcn_s_setprio(0);
    asm volatile("s_waitcnt lgkmcnt(0)" ::: "memory");
    __builtin_amdgcn_sched_barrier(0);
  }
#undef G2_STAGE

  float* orow = out + (size_t)e * T_E * D_IN;
  const int q4 = qs * 4;
#pragma unroll
  for (int mi = 0; mi < 8; ++mi) {
    const int row = m0 + wm * 128 + mi * 16 + q4;
#pragma unroll
    for (int ni = 0; ni < 4; ++ni) {
      const int col = n0 + wn * 64 + ni * 16 + lm;
#pragma unroll
      for (int r = 0; r < 4; ++r)
        orow[(size_t)(row + r) * D_IN + col] = acc[mi][ni][r];
    }
  }
}

// ---------------------------------------------------------------------------
extern "C" void kernel_launch(void* const* d_in, const int* in_sizes, int n_in,
                              void* d_out, int out_size, void* d_ws, size_t ws_size,
                              hipStream_t stream) {
  const float* x  = (const float*)d_in[0];   // [16384][2048]
  const float* w1 = (const float*)d_in[1];   // [8192][2048]
  const float* w2 = (const float*)d_in[2];
  const float* w3 = (const float*)d_in[3];
  float* out = (float*)d_out;

  // one-time: allow 128KB dynamic LDS for the gemm kernels
  static bool attr_done = false;
  if (!attr_done) {
    hipFuncSetAttribute(reinterpret_cast<const void*>(gemm1_kernel),
                        hipFuncAttributeMaxDynamicSharedMemorySize, 131072);
    hipFuncSetAttribute(reinterpret_cast<const void*>(gemm2_kernel),
                        hipFuncAttributeMaxDynamicSharedMemorySize, 131072);
    attr_done = true;
  }

  // workspace layout (bytes)
  char* ws = (char*)d_ws;
  unsigned short* xb  = (unsigned short*)(ws);                       // 64 MB
  unsigned short* w1b = (unsigned short*)(ws + 67108864);            // 32 MB
  unsigned short* w2b = (unsigned short*)(ws + 100663296);           // 32 MB
  unsigned short* w3t = (unsigned short*)(ws + 134217728);           // 32 MB
  unsigned short* gbuf= (unsigned short*)(ws + 167772160);           // 32 MB

  // 1) convert x, w1, w2 to bf16 (single launch)
  cvt3_kernel<<<(X4 + 2 * W4) / 256, 256, 0, stream>>>(x, w1, w2, xb, w1b, w2b);

  // 2) transpose+convert w3 -> [E][D][H_E]
  transpose_w3_kernel<<<dim3(D_IN / 32, HIDDEN / 32), dim3(32, 8), 0, stream>>>(w3, w3t);

  // 3) fused sdd GEMMs + SiLU gate -> g (bf16)
  gemm1_kernel<<<NEXP * 64, 512, 131072, stream>>>(xb, w1b, w2b, gbuf);

  // 4) dsd GEMM -> out (fp32)
  gemm2_kernel<<<NEXP * 64, 512, 131072, stream>>>(gbuf, w3t, out);
}